// Round 5
// baseline (411.055 us; speedup 1.0000x reference)
//
#include <hip/hip_runtime.h>
#include <stdint.h>

// Problem: B=16, S=512, H=2048, NH=16, NKV=4, HD=128
// out = Wo-proj( softmax(rope(q) @ rope(k)^T * hd^-.5) @ v )  with GQA rep=4
//
// ws layout (f16 intermediates):
//   x_h   [8192,2048]        @ 0
//   w_h   [3072,2048]        @ 33554432  (Wq 0..2047, Wk 2048..2559, Wv 2560..3071)
//   wo_h  [2048,2048]        @ 46137344
//   q     [16,16,512,128]    @ 54525952   (RoPE fused in gemm epilogue)
//   k     [16,4,512,128]     @ 88080384   (RoPE fused)
//   vt    [16,4,128,512]     @ 96468992   (V transposed)
//   attn  [8192,2048]        @ 104857600

typedef _Float16 f16;
typedef _Float16 f16x4 __attribute__((ext_vector_type(4)));
typedef _Float16 f16x8 __attribute__((ext_vector_type(8)));
typedef float f32x4 __attribute__((ext_vector_type(4)));

#define B_   16
#define S_   512
#define H_   2048
#define NH_  16
#define NKV_ 4
#define HD_  128
#define ATT_SCALE 0.08838834764831843f
#define LOG2_10000_DIV64 0.20762050593045952f

#define AS1 __attribute__((address_space(1)))
#define AS3 __attribute__((address_space(3)))

// async global->LDS, 16B/lane. LDS dest must be wave-uniform; HW adds lane*16.
__device__ __forceinline__ void async16(const void* g, const void* l) {
  __builtin_amdgcn_global_load_lds((const AS1 unsigned int*)(uintptr_t)g,
                                   (AS3 unsigned int*)(uintptr_t)l, 16, 0, 0);
}

// ---------------- fused fp32 -> f16 cast for all 5 inputs ----------------
__global__ __launch_bounds__(256) void cast_all(const float* __restrict__ x,
                                                const float* __restrict__ wq,
                                                const float* __restrict__ wk,
                                                const float* __restrict__ wv,
                                                const float* __restrict__ wo,
                                                f16* __restrict__ x_h,
                                                f16* __restrict__ w_h,
                                                f16* __restrict__ wo_h) {
  const int i = blockIdx.x * 256 + threadIdx.x;
  const float4* src;
  f16x4* dst;
  if (i < 4194304) {                 // x: 8192*2048
    src = (const float4*)x + i;            dst = (f16x4*)x_h + i;
  } else if (i < 5242880) {          // Wq: 2048*2048
    int j = i - 4194304;
    src = (const float4*)wq + j;           dst = (f16x4*)w_h + j;
  } else if (i < 5505024) {          // Wk: 512*2048
    int j = i - 5242880;
    src = (const float4*)wk + j;           dst = (f16x4*)w_h + 1048576 + j;
  } else if (i < 5767168) {          // Wv: 512*2048
    int j = i - 5505024;
    src = (const float4*)wv + j;           dst = (f16x4*)w_h + 1310720 + j;
  } else {                           // Wo: 2048*2048
    int j = i - 5767168;
    src = (const float4*)wo + j;           dst = (f16x4*)wo_h + j;
  }
  float4 v = *src;
  f16x4 o = {(f16)v.x, (f16)v.y, (f16)v.z, (f16)v.w};
  *dst = o;
}

// ---------------- 256x128 GEMM, BK=32, 8 waves, ring-3, 2 blocks/CU --------
// LDS = 3*(256+128)*32*2B = 72 KiB -> 2 blocks/CU (16 waves, 4/SIMD). The
// co-resident block fills this block's barrier/wait bubbles (the ~40% of
// cycles the 1-block/CU BK=64 version lost). Schedule per 32-K tile:
//   STAGE(t+2) -> lgkmcnt(0) -> 16 MFMA -> vmcnt(3) -> barrier -> LDFRAGS(t+1)
// vmcnt(3): outstanding there = {t+1,t+2} groups (3 each); waiting to 3
// guarantees t+1 landed while t+2 stays in flight (counted, never 0 mid-loop).
// Ring-3 race check: STAGE(t+2) overwrites buf (t-1)%3; all reads of that buf
// completed before iter-(t-1)'s end barrier. 64B LDS rows with the
// measured-conflict-free chunk swizzle c^((r>>1)&3) (round-0 pattern:
// pre-swizzled GLOBAL source, linear LDS dest, swizzled ds_read slot).
// Register discipline: single fragment set, acc 4x4 -> target <=128 VGPR so
// both blocks' 8 waves fit 4/SIMD. NO min-waves clause (round-3 lesson).
//
// MODE 1: qkv projection (RoPE fused; V transposed). MODE 0: attn @ Wo^T.
template<int MODE>
__global__ __launch_bounds__(512) void gemm_s(const f16* __restrict__ A,
                                              const f16* __restrict__ W,
                                              f16* __restrict__ qo,
                                              f16* __restrict__ ko,
                                              f16* __restrict__ vto,
                                              float* __restrict__ fout) {
  __shared__ __align__(16) f16 As[3][256 * 32];   // 3 x 16 KiB
  __shared__ __align__(16) f16 Bs[3][128 * 32];   // 3 x  8 KiB  (72 KiB total)
  const int K = 2048;
  const int NT = 64;                       // K / 32
  const int m0 = blockIdx.x * 256;
  const int n0 = blockIdx.y * 128;
  const int tid = threadIdx.x;
  const int wave = tid >> 6, lane = tid & 63;
  const int quad = lane >> 4, l15 = lane & 15;
  const int wm = wave >> 1, wn = wave & 1;  // 4M x 2N, 64x64 per wave

  // staging: A chunks G=tid, tid+512 (rows G>>2); B chunk G=tid (rows 0..127).
  // global k-chunk = (G&3) ^ ((row>>1)&3)  (involution, matches frag read)
  const f16* aptr0;
  const f16* aptr1;
  const f16* bptr;
  {
    const int r0 = tid >> 2, c0 = tid & 3;
    aptr0 = A + (size_t)(m0 + r0) * K + (c0 ^ ((r0 >> 1) & 3)) * 8;
    const int G1 = tid + 512;
    const int r1 = G1 >> 2, c1 = G1 & 3;
    aptr1 = A + (size_t)(m0 + r1) * K + (c1 ^ ((r1 >> 1) & 3)) * 8;
    const int rb = tid >> 2, cb = tid & 3;
    bptr = W + (size_t)(n0 + rb) * K + (cb ^ ((rb >> 1) & 3)) * 8;
  }
  const int ldsw = wave * 1024;            // wave's chunk-group byte base

  // fragment LDS byte offsets (within buffer 0; fixed per thread)
  int aoff[4], boff[4];
#pragma unroll
  for (int mi = 0; mi < 4; ++mi) {
    const int row = wm * 64 + mi * 16 + l15;
    aoff[mi] = row * 64 + (quad ^ ((row >> 1) & 3)) * 16;
  }
#pragma unroll
  for (int ni = 0; ni < 4; ++ni) {
    const int col = wn * 32 + (ni >> 1) * 64 + (ni & 1) * 16 + l15;
    boff[ni] = col * 64 + (quad ^ ((col >> 1) & 3)) * 16;
  }

  f32x4 acc[4][4] = {};
  f16x8 af[4], bf[4];

  auto STAGE = [&](int t, int buf) {
    async16(aptr0 + t * 32, (const char*)&As[buf][0] + ldsw);
    async16(aptr1 + t * 32, (const char*)&As[buf][0] + 8192 + ldsw);
    async16(bptr + t * 32, (const char*)&Bs[buf][0] + ldsw);
  };
  auto LDFRAGS = [&](int buf) {
    const char* Ab = (const char*)&As[buf][0];
    const char* Bb = (const char*)&Bs[buf][0];
#pragma unroll
    for (int mi = 0; mi < 4; ++mi)
      af[mi] = *reinterpret_cast<const f16x8*>(Ab + aoff[mi]);
#pragma unroll
    for (int ni = 0; ni < 4; ++ni)
      bf[ni] = *reinterpret_cast<const f16x8*>(Bb + boff[ni]);
  };

  // prologue: stage tiles 0,1
  STAGE(0, 0);
  STAGE(1, 1);
  asm volatile("s_waitcnt vmcnt(3)" ::: "memory");  // tile 0 landed
  __builtin_amdgcn_s_barrier();
  LDFRAGS(0);

  for (int t = 0; t < NT; ++t) {
    if (t + 2 < NT) STAGE(t + 2, (t + 2) % 3);
    asm volatile("s_waitcnt lgkmcnt(0)" ::: "memory");  // af/bf ready
    __builtin_amdgcn_sched_barrier(0);
    __builtin_amdgcn_s_setprio(1);
#pragma unroll
    for (int mi = 0; mi < 4; ++mi)
#pragma unroll
      for (int ni = 0; ni < 4; ++ni)
        acc[mi][ni] = __builtin_amdgcn_mfma_f32_16x16x32_f16(af[mi], bf[ni], acc[mi][ni], 0, 0, 0);
    __builtin_amdgcn_s_setprio(0);
    if (t + 1 < NT) {
      // t+1 resident: outstanding here = {t+1, t+2} groups -> counted wait
      if (t + 2 < NT) asm volatile("s_waitcnt vmcnt(3)" ::: "memory");
      else            asm volatile("s_waitcnt vmcnt(0)" ::: "memory");
      __builtin_amdgcn_s_barrier();   // buf (t+1) visible; reads of buf t done
      LDFRAGS((t + 1) % 3);
    }
  }

  // ---------------- epilogues ----------------
  if constexpr (MODE == 1) {
    const int b_ = m0 >> 9;  // batch (uniform per block; 256 | 512)
    if (n0 >= 2560) {
      // ---- V: no rope, store transposed [b, kh, d, s] ----
      const int h = (n0 - 2560) >> 7;
      f16* vb = vto + ((size_t)b_ * NKV_ + h) * HD_ * S_;
#pragma unroll
      for (int mi = 0; mi < 4; ++mi)
#pragma unroll
        for (int r = 0; r < 4; ++r) {
          const int s = (m0 + wm * 64 + mi * 16 + quad * 4 + r) & 511;
#pragma unroll
          for (int ni = 0; ni < 4; ++ni) {
            const int d = (ni >> 1) * 64 + wn * 32 + (ni & 1) * 16 + l15;
            vb[(size_t)d * S_ + s] = (f16)acc[mi][ni][r];
          }
        }
    } else {
      // ---- Q or K: fused RoPE, store [b, h, s, d] ----
      f16* ob = (n0 < 2048)
          ? (qo + ((size_t)b_ * NH_ + (n0 >> 7)) * S_ * HD_)
          : (ko + ((size_t)b_ * NKV_ + ((n0 - 2048) >> 7)) * S_ * HD_);
      float invf[2];
#pragma unroll
      for (int ni = 0; ni < 2; ++ni)
        invf[ni] = exp2f((float)(wn * 32 + ni * 16 + l15) * -LOG2_10000_DIV64);
#pragma unroll
      for (int mi = 0; mi < 4; ++mi)
#pragma unroll
        for (int r = 0; r < 4; ++r) {
          const int s = (m0 + wm * 64 + mi * 16 + quad * 4 + r) & 511;
          const size_t rb = (size_t)s * HD_;
#pragma unroll
          for (int ni = 0; ni < 2; ++ni) {
            const int d = wn * 32 + ni * 16 + l15;  // 0..63
            float sn, cs;
            __sincosf((float)s * invf[ni], &sn, &cs);
            const float x1 = acc[mi][ni][r], x2 = acc[mi][ni + 2][r];
            ob[rb + d] = (f16)(x1 * cs - x2 * sn);
            ob[rb + d + 64] = (f16)(x2 * cs + x1 * sn);
          }
        }
    }
  } else {
    // ---- fp32 output: out = attn @ Wo^T ----
#pragma unroll
    for (int mi = 0; mi < 4; ++mi)
#pragma unroll
      for (int ni = 0; ni < 4; ++ni) {
        const int ncol = n0 + wn * 32 + (ni >> 1) * 64 + (ni & 1) * 16 + l15;
#pragma unroll
        for (int r = 0; r < 4; ++r) {
          const int mrow = m0 + wm * 64 + mi * 16 + quad * 4 + r;
          fout[(size_t)mrow * 2048 + ncol] = acc[mi][ni][r];
        }
      }
  }
}

// ---------------- flash attention (v3, spill-fixed) ----------------
// 8 waves x 32 q-rows = 256 rows/block, grid (2,16,16)=512 blocks.
// KVBLK=64, K double-buffered in LDS, V single-buffered, Q in registers.
// NOTE: NO min-waves __launch_bounds__ clause (round-3: (512,4) capped the
// allocator at 64 VGPRs for a ~140-VGPR kernel -> 660 MB HBM spill traffic).
__global__ __launch_bounds__(512) void attn_kernel(const f16* __restrict__ q,
                                                   const f16* __restrict__ k,
                                                   const f16* __restrict__ vt,
                                                   f16* __restrict__ out) {
  __shared__ __align__(16) f16 Kb[2][64 * 128];   // [key][d], chunk c^(r&15)
  __shared__ __align__(16) f16 Vb[128 * 64];      // [d][key], chunk c^(r&7)
  __shared__ __align__(16) f16 Ps[8][32 * 64];    // per-wave P, chunk c^(r&7)

  const int qt = blockIdx.x, h = blockIdx.y, b = blockIdx.z;
  const int kvh = h >> 2;
  const int tid = threadIdx.x;
  const int wave = tid >> 6, lane = tid & 63;
  const int quad = lane >> 4, l15 = lane & 15;

  const f16* qbase = q + (((size_t)b * NH_ + h) * S_ + qt * 256) * HD_;
  const f16* kbase = k + ((size_t)b * NKV_ + kvh) * S_ * HD_;
  const f16* vbase = vt + ((size_t)b * NKV_ + kvh) * HD_ * S_;

  auto stageK = [&](int j) {
    f16* dst = &Kb[j & 1][0];
#pragma unroll
    for (int i = 0; i < 2; ++i) {
      const int L0 = i * 512 + wave * 64;          // wave-uniform base chunk
      const int L = L0 + lane;
      const int r = L >> 4, c = L & 15;
      async16(kbase + (size_t)(j * 64 + r) * HD_ + (c ^ (r & 15)) * 8,
              (const char*)dst + (size_t)L0 * 16);
    }
  };
  auto stageV = [&](int j) {
#pragma unroll
    for (int i = 0; i < 2; ++i) {
      const int L0 = i * 512 + wave * 64;
      const int L = L0 + lane;
      const int r = L >> 3, c = L & 7;
      async16(vbase + (size_t)r * S_ + j * 64 + (c ^ (r & 7)) * 8,
              (const char*)&Vb[0] + (size_t)L0 * 16);
    }
  };

  // Q fragments straight to registers (read exactly once, union covers tile)
  f16x8 aq[2][4];
#pragma unroll
  for (int mi = 0; mi < 2; ++mi)
#pragma unroll
    for (int ks = 0; ks < 4; ++ks)
      aq[mi][ks] = *reinterpret_cast<const f16x8*>(
          qbase + (size_t)(wave * 32 + mi * 16 + l15) * HD_ + ks * 32 + quad * 8);

  stageK(0);

  f32x4 O[2][8] = {};
  float mrun[2][4], lrun[2][4];
#pragma unroll
  for (int mi = 0; mi < 2; ++mi)
#pragma unroll
    for (int r = 0; r < 4; ++r) { mrun[mi][r] = -3.0e38f; lrun[mi][r] = 0.f; }

  for (int j = 0; j < 8; ++j) {
    // K[j] is the only outstanding group (plus aq at j=0): drain own, then
    // barrier -> every wave's staging portion visible to all.
    asm volatile("s_waitcnt vmcnt(0)" ::: "memory");
    __builtin_amdgcn_s_barrier();           // also: all waves done PV[j-1]
    stageV(j);                               // hides under QK^T + softmax

    // ---- S = Q K^T for 32 q-rows x 64 keys ----
    f32x4 Sc[2][4] = {};
#pragma unroll
    for (int ks = 0; ks < 4; ++ks) {
      f16x8 bk[4];
#pragma unroll
      for (int ni = 0; ni < 4; ++ni) {
        const int row = ni * 16 + l15;
        bk[ni] = *reinterpret_cast<const f16x8*>(
            &Kb[j & 1][row * 128 + (((ks * 4 + quad) ^ l15) & 15) * 8]);
      }
#pragma unroll
      for (int mi = 0; mi < 2; ++mi)
#pragma unroll
        for (int ni = 0; ni < 4; ++ni)
          Sc[mi][ni] = __builtin_amdgcn_mfma_f32_16x16x32_f16(aq[mi][ks], bk[ni], Sc[mi][ni], 0, 0, 0);
    }

    // ---- online softmax (row = mi*16 + quad*4 + r, col = ni*16 + l15) ----
#pragma unroll
    for (int mi = 0; mi < 2; ++mi)
#pragma unroll
      for (int r = 0; r < 4; ++r) {
        float mx = fmaxf(fmaxf(Sc[mi][0][r], Sc[mi][1][r]),
                         fmaxf(Sc[mi][2][r], Sc[mi][3][r]));
        mx *= ATT_SCALE;
#pragma unroll
        for (int off = 1; off < 16; off <<= 1) mx = fmaxf(mx, __shfl_xor(mx, off));
        const float mnew = fmaxf(mrun[mi][r], mx);
        const float alpha = __expf(mrun[mi][r] - mnew);
        float rs = 0.f;
#pragma unroll
        for (int ni = 0; ni < 4; ++ni) {
          const float pv = __expf(Sc[mi][ni][r] * ATT_SCALE - mnew);
          Sc[mi][ni][r] = pv;
          rs += pv;
        }
#pragma unroll
        for (int off = 1; off < 16; off <<= 1) rs += __shfl_xor(rs, off);
        lrun[mi][r] = lrun[mi][r] * alpha + rs;
        mrun[mi][r] = mnew;
#pragma unroll
        for (int ni = 0; ni < 8; ++ni) O[mi][ni][r] *= alpha;
        const int rowl = mi * 16 + quad * 4 + r;
#pragma unroll
        for (int ni = 0; ni < 4; ++ni) {
          const int col = ni * 16 + l15;
          Ps[wave][rowl * 64 + (((ni * 2 + (l15 >> 3)) ^ (rowl & 7)) << 3) + (l15 & 7)] =
              (f16)Sc[mi][ni][r];
        }
      }

    // V[j] landed? (K[j+1] not yet issued -> vmcnt(0) is exact & cheap here)
    asm volatile("s_waitcnt vmcnt(0)" ::: "memory");
    __builtin_amdgcn_s_barrier();           // Vb visible to all waves
    if (j < 7) stageK(j + 1);                // hides under PV + next QK^T

    // ---- O += P V (ks-outer, ni-inner: each bv read once, shared by mi) ----
#pragma unroll
    for (int ks = 0; ks < 2; ++ks) {
      f16x8 ap[2];
#pragma unroll
      for (int mi = 0; mi < 2; ++mi) {
        const int rowl = mi * 16 + l15;
        ap[mi] = *reinterpret_cast<const f16x8*>(
            &Ps[wave][rowl * 64 + (((ks * 4 + quad) ^ (l15 & 7)) << 3)]);
      }
#pragma unroll
      for (int ni = 0; ni < 8; ++ni) {
        const int row = ni * 16 + l15;
        const f16x8 bv = *reinterpret_cast<const f16x8*>(
            &Vb[row * 64 + (((ks * 4 + quad) ^ (l15 & 7)) << 3)]);
#pragma unroll
        for (int mi = 0; mi < 2; ++mi)
          O[mi][ni] = __builtin_amdgcn_mfma_f32_16x16x32_f16(ap[mi], bv, O[mi][ni], 0, 0, 0);
      }
    }
  }

  // epilogue: normalize, write attn[b, s, h*128 + d]
#pragma unroll
  for (int mi = 0; mi < 2; ++mi)
#pragma unroll
    for (int r = 0; r < 4; ++r) {
      const float inv = 1.f / lrun[mi][r];
      const int srow = qt * 256 + wave * 32 + mi * 16 + quad * 4 + r;
#pragma unroll
      for (int ni = 0; ni < 8; ++ni)
        out[((size_t)b * S_ + srow) * H_ + h * HD_ + ni * 16 + l15] = (f16)(O[mi][ni][r] * inv);
    }
}

extern "C" void kernel_launch(void* const* d_in, const int* in_sizes, int n_in,
                              void* d_out, int out_size, void* d_ws, size_t ws_size,
                              hipStream_t stream) {
  const float* x = (const float*)d_in[0];
  const float* Wq = (const float*)d_in[1];
  const float* Wk = (const float*)d_in[2];
  const float* Wv = (const float*)d_in[3];
  const float* Wo = (const float*)d_in[4];
  float* out = (float*)d_out;
  char* ws = (char*)d_ws;

  f16* x_h  = (f16*)(ws + 0);
  f16* w_h  = (f16*)(ws + 33554432);
  f16* wo_h = (f16*)(ws + 46137344);
  f16* qb   = (f16*)(ws + 54525952);
  f16* kb   = (f16*)(ws + 88080384);
  f16* vtb  = (f16*)(ws + 96468992);
  f16* attn = (f16*)(ws + 104857600);  // needs ws_size >= 138412032

  cast_all<<<26624, 256, 0, stream>>>(x, Wq, Wk, Wv, Wo, x_h, w_h, wo_h);
  gemm_s<1><<<dim3(32, 24), 512, 0, stream>>>(x_h, w_h, qb, kb, vtb, nullptr);
  attn_kernel<<<dim3(2, 16, 16), 512, 0, stream>>>(qb, kb, vtb, attn);
  gemm_s<0><<<dim3(32, 16), 512, 0, stream>>>(attn, wo_h, nullptr, nullptr, nullptr, out);
}

// Round 6
// 408.869 us; speedup vs baseline: 1.0053x; 1.0053x over previous
//
#include <hip/hip_runtime.h>
#include <stdint.h>

// Problem: B=16, S=512, H=2048, NH=16, NKV=4, HD=128
// out = Wo-proj( softmax(rope(q) @ rope(k)^T * hd^-.5) @ v )  with GQA rep=4
//
// ws layout (f16 intermediates):
//   x_h   [8192,2048]        @ 0
//   w_h   [3072,2048]        @ 33554432  (Wq 0..2047, Wk 2048..2559, Wv 2560..3071)
//   wo_h  [2048,2048]        @ 46137344
//   q     [16,16,512,128]    @ 54525952   (RoPE fused in gemm epilogue)
//   k     [16,4,512,128]     @ 88080384   (RoPE fused)
//   vt    [16,4,128,512]     @ 96468992   (V transposed)
//   attn  [8192,2048]        @ 104857600

typedef _Float16 f16;
typedef _Float16 f16x4 __attribute__((ext_vector_type(4)));
typedef _Float16 f16x8 __attribute__((ext_vector_type(8)));
typedef float f32x4 __attribute__((ext_vector_type(4)));

#define B_   16
#define S_   512
#define H_   2048
#define NH_  16
#define NKV_ 4
#define HD_  128
#define ATT_SCALE 0.08838834764831843f
#define LOG2_10000_DIV64 0.20762050593045952f

#define AS1 __attribute__((address_space(1)))
#define AS3 __attribute__((address_space(3)))

// async global->LDS, 16B/lane. LDS dest must be wave-uniform; HW adds lane*16.
__device__ __forceinline__ void async16(const void* g, const void* l) {
  __builtin_amdgcn_global_load_lds((const AS1 unsigned int*)(uintptr_t)g,
                                   (AS3 unsigned int*)(uintptr_t)l, 16, 0, 0);
}

// ---------------- fused fp32 -> f16 cast for all 5 inputs ----------------
__global__ __launch_bounds__(256) void cast_all(const float* __restrict__ x,
                                                const float* __restrict__ wq,
                                                const float* __restrict__ wk,
                                                const float* __restrict__ wv,
                                                const float* __restrict__ wo,
                                                f16* __restrict__ x_h,
                                                f16* __restrict__ w_h,
                                                f16* __restrict__ wo_h) {
  const int i = blockIdx.x * 256 + threadIdx.x;
  const float4* src;
  f16x4* dst;
  if (i < 4194304) {                 // x: 8192*2048
    src = (const float4*)x + i;            dst = (f16x4*)x_h + i;
  } else if (i < 5242880) {          // Wq: 2048*2048
    int j = i - 4194304;
    src = (const float4*)wq + j;           dst = (f16x4*)w_h + j;
  } else if (i < 5505024) {          // Wk: 512*2048
    int j = i - 5242880;
    src = (const float4*)wk + j;           dst = (f16x4*)w_h + 1048576 + j;
  } else if (i < 5767168) {          // Wv: 512*2048
    int j = i - 5505024;
    src = (const float4*)wv + j;           dst = (f16x4*)w_h + 1310720 + j;
  } else {                           // Wo: 2048*2048
    int j = i - 5767168;
    src = (const float4*)wo + j;           dst = (f16x4*)wo_h + j;
  }
  float4 v = *src;
  f16x4 o = {(f16)v.x, (f16)v.y, (f16)v.z, (f16)v.w};
  *dst = o;
}

// ---------------- 256x128 GEMM, BK=32, 8 waves, ring-3, 2 blocks/CU --------
// Round-5 found 2-blocks/CU blocked by REGISTERS on the unified gfx950 RF:
// 68 VGPR + 64 AGPR(acc) = 132 > 128 -> 3 waves/SIMD -> only 1 block fit.
// Fix here: the frag-read swizzle slot quad^((row>>1)&3) is IDENTICAL for
// every fragment (mi*16 and wm*64 are 0 mod 4 after >>1), so the 8 offsets
// collapse to ONE base + compile-time ds_read offset immediates -> ~6 fewer
// VGPRs. __launch_bounds__(512,4) then pins 4 waves/SIMD (<=128 unified
// regs/wave: 64 AGPR + <=64 VGPR). 72 KiB LDS x2 = 144 <= 160 KiB. The
// co-resident block's MFMAs cover this block's barrier + ds-latency bubbles.
// Schedule per 32-K tile (counted vmcnt, never 0 mid-loop):
//   STAGE(t+2) -> lgkmcnt(0) -> 16 MFMA -> vmcnt(3) -> barrier -> LDFRAGS(t+1)
// Ring-3 race check: STAGE(t+2) overwrites buf (t-1)%3; all reads of that
// buf completed before iter-(t-1)'s end barrier.
//
// MODE 1: qkv projection (RoPE fused; V transposed). MODE 0: attn @ Wo^T.
template<int MODE>
__global__ __launch_bounds__(512, 4) void gemm_s(const f16* __restrict__ A,
                                                 const f16* __restrict__ W,
                                                 f16* __restrict__ qo,
                                                 f16* __restrict__ ko,
                                                 f16* __restrict__ vto,
                                                 float* __restrict__ fout) {
  __shared__ __align__(16) f16 As[3][256 * 32];   // 3 x 16 KiB
  __shared__ __align__(16) f16 Bs[3][128 * 32];   // 3 x  8 KiB  (72 KiB total)
  const int K = 2048;
  const int NT = 64;                       // K / 32
  const int m0 = blockIdx.x * 256;
  const int n0 = blockIdx.y * 128;
  const int tid = threadIdx.x;
  const int wave = tid >> 6, lane = tid & 63;
  const int quad = lane >> 4, l15 = lane & 15;
  const int wm = wave >> 1, wn = wave & 1;  // 4M x 2N, 64x64 per wave

  // staging: A chunks G=tid, tid+512 (rows G>>2); B chunk G=tid (rows 0..127).
  // global k-chunk = (G&3) ^ ((row>>1)&3)  (involution, matches frag read)
  const f16* aptr0;
  const f16* aptr1;
  const f16* bptr;
  {
    const int r0 = tid >> 2, c0 = tid & 3;
    aptr0 = A + (size_t)(m0 + r0) * K + (c0 ^ ((r0 >> 1) & 3)) * 8;
    const int G1 = tid + 512;
    const int r1 = G1 >> 2, c1 = G1 & 3;
    aptr1 = A + (size_t)(m0 + r1) * K + (c1 ^ ((r1 >> 1) & 3)) * 8;
    const int rb = tid >> 2, cb = tid & 3;
    bptr = W + (size_t)(n0 + rb) * K + (cb ^ ((rb >> 1) & 3)) * 8;
  }
  const int ldsw = wave * 1024;            // wave's chunk-group byte base

  // single frag base per matrix; all 8 reads use compile-time immediates.
  // slot = quad ^ ((row>>1)&3) with row = {wm*64|wn*32 etc} + k*16 + l15:
  // (row>>1)&3 == (l15>>1)&3 for every fragment.
  const int swzb = (quad ^ ((l15 >> 1) & 3)) * 16;     // byte slot
  const int abase = (wm * 64 + l15) * 64 + swzb;
  const int bbase = (wn * 32 + l15) * 64 + swzb;

  f32x4 acc[4][4] = {};
  f16x8 af[4], bf[4];

  auto STAGE = [&](int t, int buf) {
    async16(aptr0 + t * 32, (const char*)&As[buf][0] + ldsw);
    async16(aptr1 + t * 32, (const char*)&As[buf][0] + 8192 + ldsw);
    async16(bptr + t * 32, (const char*)&Bs[buf][0] + ldsw);
  };
  auto LDFRAGS = [&](int buf) {
    const char* Ab = (const char*)&As[buf][0] + abase;
    const char* Bb = (const char*)&Bs[buf][0] + bbase;
    af[0] = *reinterpret_cast<const f16x8*>(Ab);           // mi*16 rows = 1024B
    af[1] = *reinterpret_cast<const f16x8*>(Ab + 1024);
    af[2] = *reinterpret_cast<const f16x8*>(Ab + 2048);
    af[3] = *reinterpret_cast<const f16x8*>(Ab + 3072);
    bf[0] = *reinterpret_cast<const f16x8*>(Bb);           // ni: (ni>>1)*4096+(ni&1)*1024
    bf[1] = *reinterpret_cast<const f16x8*>(Bb + 1024);
    bf[2] = *reinterpret_cast<const f16x8*>(Bb + 4096);
    bf[3] = *reinterpret_cast<const f16x8*>(Bb + 5120);
  };

  // prologue: stage tiles 0,1
  STAGE(0, 0);
  STAGE(1, 1);
  asm volatile("s_waitcnt vmcnt(3)" ::: "memory");  // tile 0 landed
  __builtin_amdgcn_s_barrier();
  LDFRAGS(0);

  for (int t = 0; t < NT; ++t) {
    if (t + 2 < NT) STAGE(t + 2, (t + 2) % 3);
    asm volatile("s_waitcnt lgkmcnt(0)" ::: "memory");  // af/bf ready
    __builtin_amdgcn_sched_barrier(0);
    __builtin_amdgcn_s_setprio(1);
#pragma unroll
    for (int mi = 0; mi < 4; ++mi)
#pragma unroll
      for (int ni = 0; ni < 4; ++ni)
        acc[mi][ni] = __builtin_amdgcn_mfma_f32_16x16x32_f16(af[mi], bf[ni], acc[mi][ni], 0, 0, 0);
    __builtin_amdgcn_s_setprio(0);
    if (t + 1 < NT) {
      // t+1 resident: outstanding here = {t+1, t+2} groups -> counted wait
      if (t + 2 < NT) asm volatile("s_waitcnt vmcnt(3)" ::: "memory");
      else            asm volatile("s_waitcnt vmcnt(0)" ::: "memory");
      __builtin_amdgcn_s_barrier();   // buf (t+1) visible; reads of buf t done
      LDFRAGS((t + 1) % 3);
    }
  }

  // ---------------- epilogues ----------------
  if constexpr (MODE == 1) {
    const int b_ = m0 >> 9;  // batch (uniform per block; 256 | 512)
    if (n0 >= 2560) {
      // ---- V: no rope, store transposed [b, kh, d, s] ----
      const int h = (n0 - 2560) >> 7;
      f16* vb = vto + ((size_t)b_ * NKV_ + h) * HD_ * S_;
#pragma unroll
      for (int mi = 0; mi < 4; ++mi)
#pragma unroll
        for (int r = 0; r < 4; ++r) {
          const int s = (m0 + wm * 64 + mi * 16 + quad * 4 + r) & 511;
#pragma unroll
          for (int ni = 0; ni < 4; ++ni) {
            const int d = (ni >> 1) * 64 + wn * 32 + (ni & 1) * 16 + l15;
            vb[(size_t)d * S_ + s] = (f16)acc[mi][ni][r];
          }
        }
    } else {
      // ---- Q or K: fused RoPE, store [b, h, s, d] ----
      f16* ob = (n0 < 2048)
          ? (qo + ((size_t)b_ * NH_ + (n0 >> 7)) * S_ * HD_)
          : (ko + ((size_t)b_ * NKV_ + ((n0 - 2048) >> 7)) * S_ * HD_);
      float invf[2];
#pragma unroll
      for (int ni = 0; ni < 2; ++ni)
        invf[ni] = exp2f((float)(wn * 32 + ni * 16 + l15) * -LOG2_10000_DIV64);
#pragma unroll
      for (int mi = 0; mi < 4; ++mi)
#pragma unroll
        for (int r = 0; r < 4; ++r) {
          const int s = (m0 + wm * 64 + mi * 16 + quad * 4 + r) & 511;
          const size_t rb = (size_t)s * HD_;
#pragma unroll
          for (int ni = 0; ni < 2; ++ni) {
            const int d = wn * 32 + ni * 16 + l15;  // 0..63
            float sn, cs;
            __sincosf((float)s * invf[ni], &sn, &cs);
            const float x1 = acc[mi][ni][r], x2 = acc[mi][ni + 2][r];
            ob[rb + d] = (f16)(x1 * cs - x2 * sn);
            ob[rb + d + 64] = (f16)(x2 * cs + x1 * sn);
          }
        }
    }
  } else {
    // ---- fp32 output: out = attn @ Wo^T ----
#pragma unroll
    for (int mi = 0; mi < 4; ++mi)
#pragma unroll
      for (int ni = 0; ni < 4; ++ni) {
        const int ncol = n0 + wn * 32 + (ni >> 1) * 64 + (ni & 1) * 16 + l15;
#pragma unroll
        for (int r = 0; r < 4; ++r) {
          const int mrow = m0 + wm * 64 + mi * 16 + quad * 4 + r;
          fout[(size_t)mrow * 2048 + ncol] = acc[mi][ni][r];
        }
      }
  }
}

// ---------------- flash attention (v3, spill-fixed) ----------------
// 8 waves x 32 q-rows = 256 rows/block, grid (2,16,16)=512 blocks.
// KVBLK=64, K double-buffered in LDS, V single-buffered, Q in registers.
// NOTE: NO min-waves __launch_bounds__ clause (round-3: (512,4) capped the
// allocator at 64 VGPRs for a ~140-VGPR kernel -> 660 MB HBM spill traffic).
__global__ __launch_bounds__(512) void attn_kernel(const f16* __restrict__ q,
                                                   const f16* __restrict__ k,
                                                   const f16* __restrict__ vt,
                                                   f16* __restrict__ out) {
  __shared__ __align__(16) f16 Kb[2][64 * 128];   // [key][d], chunk c^(r&15)
  __shared__ __align__(16) f16 Vb[128 * 64];      // [d][key], chunk c^(r&7)
  __shared__ __align__(16) f16 Ps[8][32 * 64];    // per-wave P, chunk c^(r&7)

  const int qt = blockIdx.x, h = blockIdx.y, b = blockIdx.z;
  const int kvh = h >> 2;
  const int tid = threadIdx.x;
  const int wave = tid >> 6, lane = tid & 63;
  const int quad = lane >> 4, l15 = lane & 15;

  const f16* qbase = q + (((size_t)b * NH_ + h) * S_ + qt * 256) * HD_;
  const f16* kbase = k + ((size_t)b * NKV_ + kvh) * S_ * HD_;
  const f16* vbase = vt + ((size_t)b * NKV_ + kvh) * HD_ * S_;

  auto stageK = [&](int j) {
    f16* dst = &Kb[j & 1][0];
#pragma unroll
    for (int i = 0; i < 2; ++i) {
      const int L0 = i * 512 + wave * 64;          // wave-uniform base chunk
      const int L = L0 + lane;
      const int r = L >> 4, c = L & 15;
      async16(kbase + (size_t)(j * 64 + r) * HD_ + (c ^ (r & 15)) * 8,
              (const char*)dst + (size_t)L0 * 16);
    }
  };
  auto stageV = [&](int j) {
#pragma unroll
    for (int i = 0; i < 2; ++i) {
      const int L0 = i * 512 + wave * 64;
      const int L = L0 + lane;
      const int r = L >> 3, c = L & 7;
      async16(vbase + (size_t)r * S_ + j * 64 + (c ^ (r & 7)) * 8,
              (const char*)&Vb[0] + (size_t)L0 * 16);
    }
  };

  // Q fragments straight to registers (read exactly once, union covers tile)
  f16x8 aq[2][4];
#pragma unroll
  for (int mi = 0; mi < 2; ++mi)
#pragma unroll
    for (int ks = 0; ks < 4; ++ks)
      aq[mi][ks] = *reinterpret_cast<const f16x8*>(
          qbase + (size_t)(wave * 32 + mi * 16 + l15) * HD_ + ks * 32 + quad * 8);

  stageK(0);

  f32x4 O[2][8] = {};
  float mrun[2][4], lrun[2][4];
#pragma unroll
  for (int mi = 0; mi < 2; ++mi)
#pragma unroll
    for (int r = 0; r < 4; ++r) { mrun[mi][r] = -3.0e38f; lrun[mi][r] = 0.f; }

  for (int j = 0; j < 8; ++j) {
    // K[j] is the only outstanding group (plus aq at j=0): drain own, then
    // barrier -> every wave's staging portion visible to all.
    asm volatile("s_waitcnt vmcnt(0)" ::: "memory");
    __builtin_amdgcn_s_barrier();           // also: all waves done PV[j-1]
    stageV(j);                               // hides under QK^T + softmax

    // ---- S = Q K^T for 32 q-rows x 64 keys ----
    f32x4 Sc[2][4] = {};
#pragma unroll
    for (int ks = 0; ks < 4; ++ks) {
      f16x8 bk[4];
#pragma unroll
      for (int ni = 0; ni < 4; ++ni) {
        const int row = ni * 16 + l15;
        bk[ni] = *reinterpret_cast<const f16x8*>(
            &Kb[j & 1][row * 128 + (((ks * 4 + quad) ^ l15) & 15) * 8]);
      }
#pragma unroll
      for (int mi = 0; mi < 2; ++mi)
#pragma unroll
        for (int ni = 0; ni < 4; ++ni)
          Sc[mi][ni] = __builtin_amdgcn_mfma_f32_16x16x32_f16(aq[mi][ks], bk[ni], Sc[mi][ni], 0, 0, 0);
    }

    // ---- online softmax (row = mi*16 + quad*4 + r, col = ni*16 + l15) ----
#pragma unroll
    for (int mi = 0; mi < 2; ++mi)
#pragma unroll
      for (int r = 0; r < 4; ++r) {
        float mx = fmaxf(fmaxf(Sc[mi][0][r], Sc[mi][1][r]),
                         fmaxf(Sc[mi][2][r], Sc[mi][3][r]));
        mx *= ATT_SCALE;
#pragma unroll
        for (int off = 1; off < 16; off <<= 1) mx = fmaxf(mx, __shfl_xor(mx, off));
        const float mnew = fmaxf(mrun[mi][r], mx);
        const float alpha = __expf(mrun[mi][r] - mnew);
        float rs = 0.f;
#pragma unroll
        for (int ni = 0; ni < 4; ++ni) {
          const float pv = __expf(Sc[mi][ni][r] * ATT_SCALE - mnew);
          Sc[mi][ni][r] = pv;
          rs += pv;
        }
#pragma unroll
        for (int off = 1; off < 16; off <<= 1) rs += __shfl_xor(rs, off);
        lrun[mi][r] = lrun[mi][r] * alpha + rs;
        mrun[mi][r] = mnew;
#pragma unroll
        for (int ni = 0; ni < 8; ++ni) O[mi][ni][r] *= alpha;
        const int rowl = mi * 16 + quad * 4 + r;
#pragma unroll
        for (int ni = 0; ni < 4; ++ni) {
          const int col = ni * 16 + l15;
          Ps[wave][rowl * 64 + (((ni * 2 + (l15 >> 3)) ^ (rowl & 7)) << 3) + (l15 & 7)] =
              (f16)Sc[mi][ni][r];
        }
      }

    // V[j] landed? (K[j+1] not yet issued -> vmcnt(0) is exact & cheap here)
    asm volatile("s_waitcnt vmcnt(0)" ::: "memory");
    __builtin_amdgcn_s_barrier();           // Vb visible to all waves
    if (j < 7) stageK(j + 1);                // hides under PV + next QK^T

    // ---- O += P V (ks-outer, ni-inner: each bv read once, shared by mi) ----
#pragma unroll
    for (int ks = 0; ks < 2; ++ks) {
      f16x8 ap[2];
#pragma unroll
      for (int mi = 0; mi < 2; ++mi) {
        const int rowl = mi * 16 + l15;
        ap[mi] = *reinterpret_cast<const f16x8*>(
            &Ps[wave][rowl * 64 + (((ks * 4 + quad) ^ (l15 & 7)) << 3)]);
      }
#pragma unroll
      for (int ni = 0; ni < 8; ++ni) {
        const int row = ni * 16 + l15;
        const f16x8 bv = *reinterpret_cast<const f16x8*>(
            &Vb[row * 64 + (((ks * 4 + quad) ^ (l15 & 7)) << 3)]);
#pragma unroll
        for (int mi = 0; mi < 2; ++mi)
          O[mi][ni] = __builtin_amdgcn_mfma_f32_16x16x32_f16(ap[mi], bv, O[mi][ni], 0, 0, 0);
      }
    }
  }

  // epilogue: normalize, write attn[b, s, h*128 + d]
#pragma unroll
  for (int mi = 0; mi < 2; ++mi)
#pragma unroll
    for (int r = 0; r < 4; ++r) {
      const float inv = 1.f / lrun[mi][r];
      const int srow = qt * 256 + wave * 32 + mi * 16 + quad * 4 + r;
#pragma unroll
      for (int ni = 0; ni < 8; ++ni)
        out[((size_t)b * S_ + srow) * H_ + h * HD_ + ni * 16 + l15] = (f16)(O[mi][ni][r] * inv);
    }
}

extern "C" void kernel_launch(void* const* d_in, const int* in_sizes, int n_in,
                              void* d_out, int out_size, void* d_ws, size_t ws_size,
                              hipStream_t stream) {
  const float* x = (const float*)d_in[0];
  const float* Wq = (const float*)d_in[1];
  const float* Wk = (const float*)d_in[2];
  const float* Wv = (const float*)d_in[3];
  const float* Wo = (const float*)d_in[4];
  float* out = (float*)d_out;
  char* ws = (char*)d_ws;

  f16* x_h  = (f16*)(ws + 0);
  f16* w_h  = (f16*)(ws + 33554432);
  f16* wo_h = (f16*)(ws + 46137344);
  f16* qb   = (f16*)(ws + 54525952);
  f16* kb   = (f16*)(ws + 88080384);
  f16* vtb  = (f16*)(ws + 96468992);
  f16* attn = (f16*)(ws + 104857600);  // needs ws_size >= 138412032

  cast_all<<<26624, 256, 0, stream>>>(x, Wq, Wk, Wv, Wo, x_h, w_h, wo_h);
  gemm_s<1><<<dim3(32, 24), 512, 0, stream>>>(x_h, w_h, qb, kb, vtb, nullptr);
  attn_kernel<<<dim3(2, 16, 16), 512, 0, stream>>>(qb, kb, vtb, attn);
  gemm_s<0><<<dim3(32, 16), 512, 0, stream>>>(attn, wo_h, nullptr, nullptr, nullptr, out);
}